// Round 6
// baseline (180.347 us; speedup 1.0000x reference)
//
#include <hip/hip_runtime.h>

// x: (B, C, D, H, W) float32; out: (B, D, H, W) float32 = log(det(I+grad u))^2.
constexpr int B = 2, C = 3, D = 128, H = 192, W = 192;
constexpr int sH = W;          // stride of h (elements)
constexpr int sD = H * W;      // stride of d
constexpr int sC = D * H * W;  // stride of c
constexpr int sB = C * sC;     // stride of b

constexpr int THREADS = 384;     // 6 waves
constexpr int TH = 8;            // tile h-rows
constexpr int TWQ = W / 4;       // 48 f4-groups = FULL W row (no w-seams)
constexpr int DC = 8;            // d-planes marched per block
constexpr int HX = H / TH;       // 24 h-tiles
constexpr int NDC = D / DC;      // 16 d-chunks
constexpr int NB = B * NDC * HX; // 768 blocks = exactly 3/CU, zero tail
constexpr int ROWS = TH + 2;     // 10 staged rows (h-halo)
constexpr int RSTR = TWQ + 1;    // 49 f4 row stride (+1 pad vs bank aliasing)
constexpr int CH_STR = ROWS * RSTR;    // 490 f4 per channel
constexpr int BUFSZ = C * CH_STR;      // 1470 f4 per buffer (23.5 KB)
constexpr int NXCD = 8;
constexpr int PERX = NB / NXCD;  // 96 logical blocks per XCD (768%8==0: bijective)

// R5: XCD-chunked swizzle only (non-temporal store dropped — suspect in two
// container failures; it was a secondary effect anyway). With linear
// round-robin, adjacent hx / dch blocks (which share halo rows / boundary
// planes) land on different XCDs -> every halo line fetched twice from HBM
// (~60 MB non-compulsory of 211 MB total). Swizzle gives XCD k the contiguous
// logical slice [k*96,(k+1)*96): all hx tiles + 4 adjacent dch chunks -> halo
// refetches become same-XCD L2 hits.
__global__ __launch_bounds__(THREADS, 4) void jac_logdet_sq(
    const float* __restrict__ x, float* __restrict__ out) {
    __shared__ float4 lds[2][BUFSZ];   // 47 KB -> 3 blocks/CU

    const int tid = threadIdx.x;
    const int tx = tid % TWQ;          // f4-group 0..47 (w)
    const int ty = tid / TWQ;          // row 0..7 (h)

    // XCD-chunked bijective swizzle (HW round-robins blockIdx.x % 8 -> XCD)
    const int bid = blockIdx.x;
    int nb = (bid % NXCD) * PERX + bid / NXCD;

    const int hx = nb % HX; nb /= HX;
    const int dch = nb % NDC;
    const int b = nb / NDC;

    const int d0 = dch * DC;
    const int h0 = hx * TH;
    const int h = h0 + ty;
    const int w0 = tx * 4;

    const float* pb = x + b * sB;
    const int cidx = h * sH + w0;      // (h,w) offset within one (c,d) plane

    // halo staging role (tid < 288): channel hc, top/bottom row hrr, col htx
    const int hc = tid / 96;
    const int hrem = tid % 96;
    const int hrr = hrem / TWQ;        // 0=top halo, 1=bottom halo
    const int htx = hrem % TWQ;
    const int hh = hrr ? ((h0 + TH < H) ? h0 + TH : H - 1)
                       : ((h0 > 0) ? h0 - 1 : 0);
    const int hidx = hh * sH + htx * 4;
    const int hlds = hc * CH_STR + (hrr ? (TH + 1) : 0) * RSTR + htx;
    const bool halo = (tid < 288);

    const float chc = (h > 0 && h < H - 1) ? 0.5f : 1.0f;

    float4 cm[3], c0[3], cp[3], cn[3];
    float4 hv0, hvp, hvn;

    // ---- prologue: window {d0-1, d0, d0+1}; stage d0 + halo(d0) ----
    const int dm = (d0 > 0) ? d0 - 1 : 0;   // d0+1 <= D-1 always (DC >= 2)
#pragma unroll
    for (int c = 0; c < 3; ++c) {
        c0[c] = *(const float4*)(pb + c * sC + d0 * sD + cidx);
        cm[c] = *(const float4*)(pb + c * sC + dm * sD + cidx);
        cp[c] = *(const float4*)(pb + c * sC + (d0 + 1) * sD + cidx);
    }
    if (halo) {
        hv0 = *(const float4*)(pb + hc * sC + d0 * sD + hidx);
        hvp = *(const float4*)(pb + hc * sC + (d0 + 1) * sD + hidx);
    }
#pragma unroll
    for (int c = 0; c < 3; ++c)
        lds[0][c * CH_STR + (ty + 1) * RSTR + tx] = c0[c];
    if (halo) lds[0][hlds] = hv0;
    __syncthreads();

    int obase = ((b * D + d0) * H + h) * W + w0;

#pragma unroll
    for (int dd = 0; dd < DC; ++dd) {
        const int d = d0 + dd;
        const float cdc = (d > 0 && d < D - 1) ? 0.5f : 1.0f;
        const float4* bufc = lds[dd & 1];        // plane d (staged last iter)

        // ---- d-gradient first (frees cm before cn lands) ----
        float gd[3][4], gh[3][4], gw[3][4];
#pragma unroll
        for (int c = 0; c < 3; ++c) {
            gd[c][0] = (cp[c].x - cm[c].x) * cdc;
            gd[c][1] = (cp[c].y - cm[c].y) * cdc;
            gd[c][2] = (cp[c].z - cm[c].z) * cdc;
            gd[c][3] = (cp[c].w - cm[c].w) * cdc;
        }

        // ---- prefetch for iter dd+1: plane d+2 regs, halo(d+2) ----
        if (dd < DC - 1) {
            const int dpp = (d + 2 < D) ? d + 2 : D - 1;
#pragma unroll
            for (int c = 0; c < 3; ++c)
                cn[c] = *(const float4*)(pb + c * sC + dpp * sD + cidx);
            if (dd < DC - 2 && halo)
                hvn = *(const float4*)(pb + hc * sC + dpp * sD + hidx);
        }

        // ---- h/w gradients from LDS (plane d) + c0 regs ----
#pragma unroll
        for (int c = 0; c < 3; ++c) {
            const float4 hp = bufc[c * CH_STR + (ty + 2) * RSTR + tx];
            const float4 hm = bufc[c * CH_STR + (ty    ) * RSTR + tx];
            gh[c][0] = (hp.x - hm.x) * chc;
            gh[c][1] = (hp.y - hm.y) * chc;
            gh[c][2] = (hp.z - hm.z) * chc;
            gh[c][3] = (hp.w - hm.w) * chc;

            // w-neighbors entirely from LDS; clamp index, value unused at edge
            const int txl = (tx > 0) ? tx - 1 : tx;
            const int txr = (tx < TWQ - 1) ? tx + 1 : tx;
            const float lft = bufc[c * CH_STR + (ty + 1) * RSTR + txl].w;
            const float rgt = bufc[c * CH_STR + (ty + 1) * RSTR + txr].x;
            gw[c][0] = (tx == 0)       ? (c0[c].y - c0[c].x)
                                       : 0.5f * (c0[c].y - lft);
            gw[c][1] = 0.5f * (c0[c].z - c0[c].x);
            gw[c][2] = 0.5f * (c0[c].w - c0[c].y);
            gw[c][3] = (tx == TWQ - 1) ? (c0[c].w - c0[c].z)
                                       : 0.5f * (rgt - c0[c].z);
        }

        float r[4];
#pragma unroll
        for (int e = 0; e < 4; ++e) {
            const float a00 = gd[0][e] + 1.0f, a01 = gd[1][e], a02 = gd[2][e];
            const float a10 = gh[0][e], a11 = gh[1][e] + 1.0f, a12 = gh[2][e];
            const float a20 = gw[0][e], a21 = gw[1][e], a22 = gw[2][e] + 1.0f;
            const float det = a00 * (a11 * a22 - a12 * a21)
                            - a01 * (a10 * a22 - a12 * a20)
                            + a02 * (a10 * a21 - a11 * a20);
            const float l = __logf(det);  // det>0; HW log, validated R3
            r[e] = l * l;
        }
        *(float4*)(out + obase) = make_float4(r[0], r[1], r[2], r[3]);
        obase += sD;

        // ---- stage plane d+1 (cp, hvp: both long-arrived) ----
        if (dd < DC - 1) {
#pragma unroll
            for (int c = 0; c < 3; ++c)
                lds[(dd + 1) & 1][c * CH_STR + (ty + 1) * RSTR + tx] = cp[c];
            if (halo) lds[(dd + 1) & 1][hlds] = hvp;
            __syncthreads();

            // rotate window (unrolled -> register-renamed)
#pragma unroll
            for (int c = 0; c < 3; ++c) {
                cm[c] = c0[c]; c0[c] = cp[c]; cp[c] = cn[c];
            }
            hvp = hvn;
        }
    }
}

extern "C" void kernel_launch(void* const* d_in, const int* in_sizes, int n_in,
                              void* d_out, int out_size, void* d_ws, size_t ws_size,
                              hipStream_t stream) {
    const float* x = (const float*)d_in[0];
    float* out = (float*)d_out;
    jac_logdet_sq<<<dim3(NB), dim3(THREADS), 0, stream>>>(x, out);
}